// Round 1
// baseline (180.683 us; speedup 1.0000x reference)
//
#include <hip/hip_runtime.h>
#include <cstdint>
#include <cstddef>

// PConv: out[b,m,c,w] = sum_k cat[b,m,k,c] * weightnet[b,m,k,w]
// cat = concat(gather(input_features, neighbor_inds), additional_features)
// B=2 N=50000 M=50000 K=16 C_IN=64 C_ADD=3 C_MID=16 -> out [2,50000,1072] f32

namespace {
constexpr int B_   = 2;
constexpr int N_   = 50000;
constexpr int M_   = 50000;
constexpr int K_   = 16;
constexpr int CIN  = 64;
constexpr int CADD = 3;
constexpr int CMID = 16;
constexpr int CTOT = CIN + CADD;      // 67
constexpr int COUT = CTOT * CMID;     // 1072
constexpr int CPAD = 72;              // LDS row stride (x4B = 288B, 16B-aligned, conflict-friendly)
constexpr int WPB  = 4;               // waves per block
constexpr int PAIRS = B_ * M_;        // 100000
}

__global__ __launch_bounds__(256, 4)
void pconv_kernel(const float* __restrict__ feat,   // [B][N][64]
                  const int*   __restrict__ inds,   // [B][M][16] (int32 per harness contract)
                  const float* __restrict__ wnet,   // [B][M][16][16]
                  const float* __restrict__ addf,   // [B][M][16][3]
                  float* __restrict__ out)          // [B][M][1072]
{
    __shared__ alignas(16) float s_cat[WPB][K_][CPAD];
    __shared__ alignas(16) float s_wn [WPB][K_][CMID];

    const int lane = threadIdx.x & 63;
    const int wid  = threadIdx.x >> 6;
    const int gwave0 = (int)((blockIdx.x * blockDim.x + threadIdx.x) >> 6);
    const int nwaves = (int)((gridDim.x * blockDim.x) >> 6);

    float (*catw)[CPAD] = s_cat[wid];
    float (*wnw)[CMID]  = s_wn[wid];

    const int k_st = lane >> 2;   // staging: row this lane loads
    const int q_st = lane & 3;    // staging: quad within row
    const int cq   = lane >> 2;   // compute: c-quad (0..15) -> c = cq*4 + i
    const int wg   = lane & 3;    // compute: w-quad (0..3)  -> w = wg*4 + j

    for (int p = gwave0; p < PAIRS; p += nwaves) {
        const int b = p / M_;
        const float* __restrict__ wnp  = wnet + (size_t)p * (K_ * CMID);
        const float* __restrict__ adp  = addf + (size_t)p * (K_ * CADD);
        const int*   __restrict__ idxp = inds + (size_t)p * K_;

        // ---- stage weightnet tile: 256 floats, one float4 per lane ----
        {
            float4 v = *reinterpret_cast<const float4*>(wnp + lane * 4);
            *reinterpret_cast<float4*>(&wnw[0][0] + lane * 4) = v;
        }
        // ---- stage gathered features: 16 rows x 64 floats (4 lanes/row) ----
        {
            const int idx = idxp[k_st];
            const float* __restrict__ row = feat + ((size_t)b * N_ + (size_t)idx) * CIN;
            #pragma unroll
            for (int j = 0; j < 4; ++j) {
                float4 v = *reinterpret_cast<const float4*>(row + j * 16 + q_st * 4);
                *reinterpret_cast<float4*>(&catw[k_st][j * 16 + q_st * 4]) = v;
            }
        }
        // ---- stage additional features: 48 floats ----
        if (lane < K_ * CADD) {
            const int k = lane / CADD;
            const int c = lane - k * CADD;
            catw[k][CIN + c] = adp[lane];
        }

        // Wave-synchronous fence: all 64 lanes' LDS writes complete (and are
        // ordered) before cross-lane LDS reads below. DS ops are in-order per
        // wave; the asm+sched_barrier stops compiler reordering.
        asm volatile("s_waitcnt lgkmcnt(0)" ::: "memory");
        __builtin_amdgcn_sched_barrier(0);

        float* __restrict__ outp = out + (size_t)p * COUT;

        // ---- phase 1: c in [0,64): 4c x 4w register tile per lane ----
        float acc[4][4];
        #pragma unroll
        for (int i = 0; i < 4; ++i)
            #pragma unroll
            for (int j = 0; j < 4; ++j) acc[i][j] = 0.f;

        #pragma unroll
        for (int k = 0; k < K_; ++k) {
            float4 a = *reinterpret_cast<const float4*>(&catw[k][cq * 4]);
            float4 w = *reinterpret_cast<const float4*>(&wnw[k][wg * 4]);
            const float av[4] = {a.x, a.y, a.z, a.w};
            const float wv[4] = {w.x, w.y, w.z, w.w};
            #pragma unroll
            for (int i = 0; i < 4; ++i)
                #pragma unroll
                for (int j = 0; j < 4; ++j)
                    acc[i][j] = fmaf(av[i], wv[j], acc[i][j]);
        }

        #pragma unroll
        for (int i = 0; i < 4; ++i) {
            float4 v;
            v.x = acc[i][0]; v.y = acc[i][1]; v.z = acc[i][2]; v.w = acc[i][3];
            *reinterpret_cast<float4*>(outp + (size_t)(cq * 4 + i) * CMID + wg * 4) = v;
        }

        // ---- phase 2: c in {64,65,66}: 48 lanes, one (c,w) each ----
        if (lane < CADD * CMID) {
            const int ci = lane >> 4;      // 0..2
            const int w  = lane & 15;      // 0..15
            float s = 0.f;
            #pragma unroll
            for (int k = 0; k < K_; ++k)
                s = fmaf(catw[k][CIN + ci], wnw[k][w], s);
            outp[(size_t)(CIN + ci) * CMID + w] = s;
        }
    }
}

extern "C" void kernel_launch(void* const* d_in, const int* in_sizes, int n_in,
                              void* d_out, int out_size, void* d_ws, size_t ws_size,
                              hipStream_t stream) {
    const float* feat = (const float*)d_in[0];
    const int*   inds = (const int*)d_in[1];
    const float* wnet = (const float*)d_in[2];
    const float* addf = (const float*)d_in[3];
    float* outp = (float*)d_out;

    dim3 grid(2048);
    dim3 block(256);
    hipLaunchKernelGGL(pconv_kernel, grid, block, 0, stream,
                       feat, inds, wnet, addf, outp);
}